// Round 1
// baseline (131.772 us; speedup 1.0000x reference)
//
#include <hip/hip_runtime.h>
#include <math.h>

// Problem constants (fixed by the reference)
#define BD   128      // batch == hidden
#define ID   1024     // img dim
#define TD   1024     // txt dim
#define NE   32768    // edges
#define HD   128      // hidden

// ---------------------------------------------------------------------------
// K1: transposes (img [128,1024]->imgT [1024,128], text likewise,
//     W1 [128,256] -> W1T [256,128]) + edge histograms (cnt_src/cnt_tgt).
// blocks 0..127: img tiles, 128..255: text tiles, 256..287: W1 tiles,
// 288..415: histogram (128 blocks x 256 thr = 32768 edges).
// ---------------------------------------------------------------------------
__global__ __launch_bounds__(256) void prep_kernel(
    const float* __restrict__ img, const float* __restrict__ text,
    const float* __restrict__ W1,
    const int* __restrict__ src, const int* __restrict__ tgt,
    float* __restrict__ imgT, float* __restrict__ textT, float* __restrict__ W1T,
    int* __restrict__ cnt_src, int* __restrict__ cnt_tgt)
{
    __shared__ float lds[32][33];   // +1 pad: conflict-free transpose
    int blk = blockIdx.x;
    if (blk < 288) {
        const float* S; float* D; int R, C, tile0;
        if (blk < 128)      { S = img;  D = imgT;  R = 128; C = 1024; tile0 = blk; }
        else if (blk < 256) { S = text; D = textT; R = 128; C = 1024; tile0 = blk - 128; }
        else                { S = W1;   D = W1T;   R = 128; C = 256;  tile0 = blk - 256; }
        int tilesPerRow = C >> 5;
        int rt = tile0 / tilesPerRow, ct = tile0 % tilesPerRow;
        int x = threadIdx.x & 31, y = threadIdx.x >> 5;   // x col, y 0..7
        #pragma unroll
        for (int k = 0; k < 4; k++) {
            int r = y + k * 8;
            lds[r][x] = S[(rt * 32 + r) * C + ct * 32 + x];
        }
        __syncthreads();
        #pragma unroll
        for (int k = 0; k < 4; k++) {
            int r = y + k * 8;
            D[(ct * 32 + r) * R + rt * 32 + x] = lds[x][r];
        }
    } else {
        int e = (blk - 288) * 256 + threadIdx.x;   // exactly covers 32768
        atomicAdd(&cnt_src[src[e]], 1);
        atomicAdd(&cnt_tgt[tgt[e]], 1);
    }
}

// ---------------------------------------------------------------------------
// K2: dual exclusive scan (1024 bins each) in one block of 1024 threads.
// Writes cur_* (fill cursors) and off_* (bucket starts for gather).
// ---------------------------------------------------------------------------
__global__ __launch_bounds__(1024) void scan_kernel(
    const int* __restrict__ cnt_src, const int* __restrict__ cnt_tgt,
    int* __restrict__ cur_src, int* __restrict__ cur_tgt,
    int* __restrict__ off_src, int* __restrict__ off_tgt)
{
    __shared__ int s[1024];
    int tid = threadIdx.x;

    int v = cnt_src[tid];
    s[tid] = v;
    __syncthreads();
    for (int off = 1; off < 1024; off <<= 1) {
        int t = (tid >= off) ? s[tid - off] : 0;
        __syncthreads();
        s[tid] += t;
        __syncthreads();
    }
    int ex = s[tid] - v;
    cur_src[tid] = ex; off_src[tid] = ex;
    __syncthreads();

    v = cnt_tgt[tid];
    s[tid] = v;
    __syncthreads();
    for (int off = 1; off < 1024; off <<= 1) {
        int t = (tid >= off) ? s[tid - off] : 0;
        __syncthreads();
        s[tid] += t;
        __syncthreads();
    }
    ex = s[tid] - v;
    cur_tgt[tid] = ex; off_tgt[tid] = ex;
}

// ---------------------------------------------------------------------------
// K3: blocks 0..127 fill CSR edge lists; blocks 128..255 compute
//   HimgT[i,h] = sum_b imgT[i,b]*W1T[b*128+h]      (+ b1[h] folded in)
//   HtxtT[t,h] = sum_b textT[t,b]*W1T[(128+b)*128+h]
// Each GEMM block: 16 rows, 256 threads, rows staged in 8 KB LDS;
// W1T reads are coalesced & broadcast across blocks (L2-hot).
// ---------------------------------------------------------------------------
__global__ __launch_bounds__(256) void fill_gemm_kernel(
    const int* __restrict__ src, const int* __restrict__ tgt,
    int* __restrict__ cur_src, int* __restrict__ cur_tgt,
    int* __restrict__ list_src, int* __restrict__ list_tgt,
    const float* __restrict__ imgT, const float* __restrict__ textT,
    const float* __restrict__ W1T, const float* __restrict__ b1,
    float* __restrict__ HimgT, float* __restrict__ HtxtT)
{
    __shared__ float rows[16 * 128];
    int blk = blockIdx.x;
    if (blk < 128) {
        int e = blk * 256 + threadIdx.x;
        int s0 = src[e];
        int p = atomicAdd(&cur_src[s0], 1);
        list_src[p] = e;
        int t0 = tgt[e];
        int q = atomicAdd(&cur_tgt[t0], 1);
        list_tgt[q] = e;
        return;
    }
    int g = blk - 128;            // 0..127
    bool isTxt = (g >= 64);
    int ibase = (g & 63) * 16;
    const float* S  = isTxt ? textT : imgT;
    const float* W  = W1T + (isTxt ? 128 * 128 : 0);
    float* Dst      = isTxt ? HtxtT : HimgT;

    const float4* s4 = (const float4*)(S + ibase * 128);
    float4* r4 = (float4*)rows;
    r4[threadIdx.x]       = s4[threadIdx.x];        // 512 float4 total
    r4[threadIdx.x + 256] = s4[threadIdx.x + 256];
    __syncthreads();

    int h  = threadIdx.x & 127;
    int iq = threadIdx.x >> 7;    // 0/1 -> rows 0-7 / 8-15
    const float* rb = rows + iq * 8 * 128;
    float acc[8] = {0.f,0.f,0.f,0.f,0.f,0.f,0.f,0.f};
    #pragma unroll 4
    for (int b = 0; b < 128; b++) {
        float wv = W[b * 128 + h];          // coalesced global, L2-hot
        #pragma unroll
        for (int r = 0; r < 8; r++)
            acc[r] += wv * rb[r * 128 + b]; // LDS broadcast reads
    }
    float bias = isTxt ? 0.f : b1[h];       // fold b1 into HimgT
    #pragma unroll
    for (int r = 0; r < 8; r++)
        Dst[(ibase + iq * 8 + r) * 128 + h] = acc[r] + bias;
}

// ---------------------------------------------------------------------------
// K4: one wave per edge: a[e] = sigmoid(w2 . relu(HimgT[src]+HtxtT[tgt]) + b2)
// (b1 already folded into HimgT). 64 lanes cover 128 h via 2 elems/lane.
// ---------------------------------------------------------------------------
__global__ __launch_bounds__(256) void edge_kernel(
    const int* __restrict__ src, const int* __restrict__ tgt,
    const float* __restrict__ HimgT, const float* __restrict__ HtxtT,
    const float* __restrict__ w2, const float* __restrict__ b2,
    float* __restrict__ a)
{
    int e = blockIdx.x * 4 + (threadIdx.x >> 6);
    int lane = threadIdx.x & 63;
    int s0 = src[e], t0 = tgt[e];
    const float* Hi = HimgT + s0 * 128;
    const float* Ht = HtxtT + t0 * 128;
    float v1 = Hi[lane]      + Ht[lane];
    float v2 = Hi[lane + 64] + Ht[lane + 64];
    float x = fmaxf(v1, 0.f) * w2[lane] + fmaxf(v2, 0.f) * w2[lane + 64];
    #pragma unroll
    for (int off = 32; off > 0; off >>= 1)
        x += __shfl_xor(x, off, 64);
    if (lane == 0)
        a[e] = 1.f / (1.f + expf(-(x + b2[0])));
}

// ---------------------------------------------------------------------------
// K5: bucket gather -> outputs. Block < 1024: attended_img row i
//   out[b*1024+i] = sum_{e in bucket_src[i]} a[e]*textT[tgt[e]*128+b]
// Block >= 1024: attended_text col t, symmetric with imgT.
// Reads coalesced (128-float rows); every output element written (zeros for
// empty buckets) so no pre-zero of d_out needed. Deterministic, atomic-free.
// ---------------------------------------------------------------------------
__global__ __launch_bounds__(128) void gather_kernel(
    const int* __restrict__ src, const int* __restrict__ tgt,
    const int* __restrict__ off_src, const int* __restrict__ off_tgt,
    const int* __restrict__ cnt_src, const int* __restrict__ cnt_tgt,
    const int* __restrict__ list_src, const int* __restrict__ list_tgt,
    const float* __restrict__ a,
    const float* __restrict__ imgT, const float* __restrict__ textT,
    float* __restrict__ out)
{
    int blk = blockIdx.x;
    int b = threadIdx.x;
    if (blk < 1024) {
        int i = blk;
        int start = off_src[i], n = cnt_src[i];
        float acc = 0.f;
        for (int p = 0; p < n; p++) {
            int e = list_src[start + p];
            int t = tgt[e];
            acc += a[e] * textT[t * 128 + b];
        }
        out[b * 1024 + i] = acc;
    } else {
        int t = blk - 1024;
        int start = off_tgt[t], n = cnt_tgt[t];
        float acc = 0.f;
        for (int p = 0; p < n; p++) {
            int e = list_tgt[start + p];
            int s0 = src[e];
            acc += a[e] * imgT[s0 * 128 + b];
        }
        out[BD * ID + b * 1024 + t] = acc;
    }
}

extern "C" void kernel_launch(void* const* d_in, const int* in_sizes, int n_in,
                              void* d_out, int out_size, void* d_ws, size_t ws_size,
                              hipStream_t stream)
{
    const float* img  = (const float*)d_in[0];   // [128,1024]
    const float* text = (const float*)d_in[1];   // [128,1024]
    const int*   src  = (const int*)  d_in[2];   // [32768]
    const int*   tgt  = (const int*)  d_in[3];   // [32768]
    const float* W1   = (const float*)d_in[4];   // [128,256]
    const float* b1   = (const float*)d_in[5];   // [128]
    const float* w2   = (const float*)d_in[6];   // [128]
    const float* b2   = (const float*)d_in[7];   // [1]
    float* out = (float*)d_out;                  // [128*1024]+[128*1024]

    // workspace layout (all re-derived every call; ws is re-poisoned by harness)
    float* imgT   = (float*)d_ws;        // 131072
    float* textT  = imgT   + 131072;     // 131072
    float* W1T    = textT  + 131072;     // 32768  ([256,128], W1T[b*128+h]=W1[h*256+b])
    float* HimgT  = W1T    + 32768;      // 131072 (b1 folded in)
    float* HtxtT  = HimgT  + 131072;     // 131072
    float* a_e    = HtxtT  + 131072;     // 32768
    int* cnt_src  = (int*)(a_e + 32768); // 1024
    int* cnt_tgt  = cnt_src + 1024;      // 1024
    int* cur_src  = cnt_tgt + 1024;      // 1024
    int* cur_tgt  = cur_src + 1024;      // 1024
    int* off_src  = cur_tgt + 1024;      // 1024
    int* off_tgt  = off_src + 1024;      // 1024
    int* list_src = off_tgt + 1024;      // 32768
    int* list_tgt = list_src + 32768;    // 32768   (total ~2.65 MB)

    hipMemsetAsync(cnt_src, 0, 2 * 1024 * sizeof(int), stream);
    prep_kernel<<<416, 256, 0, stream>>>(img, text, W1, src, tgt,
                                         imgT, textT, W1T, cnt_src, cnt_tgt);
    scan_kernel<<<1, 1024, 0, stream>>>(cnt_src, cnt_tgt,
                                        cur_src, cur_tgt, off_src, off_tgt);
    fill_gemm_kernel<<<256, 256, 0, stream>>>(src, tgt, cur_src, cur_tgt,
                                              list_src, list_tgt,
                                              imgT, textT, W1T, b1, HimgT, HtxtT);
    edge_kernel<<<8192, 256, 0, stream>>>(src, tgt, HimgT, HtxtT, w2, b2, a_e);
    gather_kernel<<<2048, 128, 0, stream>>>(src, tgt, off_src, off_tgt,
                                            cnt_src, cnt_tgt, list_src, list_tgt,
                                            a_e, imgT, textT, out);
}